// Round 4
// baseline (1042.152 us; speedup 1.0000x reference)
//
#include <hip/hip_runtime.h>
#include <hip/hip_bf16.h>
#include <cstdint>
#include <cstddef>

#define B_   32
#define L_   2048
#define C_   1024
#define H_   16
#define HD_  64
#define HID_ 256
#define OUT_ 128
#define NS_  8            // l-splits per batch
#define RPB_ (L_/NS_)     // rows per block = 256
#define RPI_ 4            // rows per barrier-iter
#define ITERS_ (RPB_/RPI_)

// ---------------- workspace layout (float offsets) ----------------
#define WS_U1   0
#define WS_U2   (WS_U1 + B_*C_)
#define WS_A1   (WS_U2 + B_*C_)
#define WS_A2   (WS_A1 + B_*H_*C_)
#define WS_CST  (WS_A2 + B_*H_*C_)
#define WS_MP   (WS_CST + B_*H_)
#define WS_ZP   (WS_MP + B_*NS_*H_)
#define WS_SP   (WS_ZP + B_*NS_*H_)
#define WS_SFIN (WS_SP + B_*NS_*H_*C_)
#define WS_VO   (WS_SFIN + B_*H_*C_)
#define WS_O    (WS_VO + B_*C_)

// ---------------- DPP wave-64 sum, result broadcast to all lanes ----------------
template <int CTRL>
__device__ __forceinline__ float dpp_add(float x) {
  int t = __builtin_amdgcn_update_dpp(0, __float_as_int(x), CTRL, 0xF, 0xF, true);
  return x + __int_as_float(t);
}
__device__ __forceinline__ float wave_sum_bcast(float x) {
  x = dpp_add<0x111>(x);  // row_shr:1
  x = dpp_add<0x112>(x);  // row_shr:2
  x = dpp_add<0x114>(x);  // row_shr:4
  x = dpp_add<0x118>(x);  // row_shr:8
  x = dpp_add<0x142>(x);  // row_bcast:15
  x = dpp_add<0x143>(x);  // row_bcast:31
  return __int_as_float(__builtin_amdgcn_readlane(__float_as_int(x), 63));
}

// ---------------- prep 1: u1 = q+q_r, u2 = q (bias+scale folded) ----------------
__global__ __launch_bounds__(256) void prep_q(
    const float* __restrict__ fvec_c, const float* __restrict__ dis_enc_c,
    const float* __restrict__ in_proj_w, const float* __restrict__ in_proj_b,
    float* __restrict__ ws) {
  int tid = blockIdx.x * 256 + threadIdx.x;      // covers B_*C_ = 32768
  int b = tid & (B_ - 1);
  int i = tid >> 5;
  const float* x = fvec_c + b * C_;
  const float* d = dis_enc_c + b * C_;           // dis_enc_c: (1,B,C)
  const float* w = in_proj_w + (size_t)i * C_;   // Wq row i
  float ax = 0.f, ad = 0.f;
  for (int k = 0; k < C_; k += 4) {
    float4 wv = *(const float4*)(w + k);
    float4 xv = *(const float4*)(x + k);
    float4 dv = *(const float4*)(d + k);
    ax += wv.x*xv.x + wv.y*xv.y + wv.z*xv.z + wv.w*xv.w;
    ad += wv.x*dv.x + wv.y*dv.y + wv.z*dv.z + wv.w*dv.w;
  }
  float q  = (ax + in_proj_b[i]) * 0.125f;       // scale = 64^-0.5
  float qr = (ad + in_proj_b[i]) * 0.125f;
  ws[WS_U1 + b*C_ + i] = q + qr;
  ws[WS_U2 + b*C_ + i] = q;
}

// ---------------- prep 2: A1[b,h,:] = Wk_h^T u1_h ; A2 = Wk_h^T u2_h ; cst ----------------
__global__ __launch_bounds__(256) void prep_A(
    const float* __restrict__ Wk, const float* __restrict__ bk,
    float* __restrict__ ws) {
  int b = blockIdx.x, h = blockIdx.y, t = threadIdx.x;
  __shared__ float su1[HD_], su2[HD_];
  if (t < HD_) {
    su1[t] = ws[WS_U1 + b*C_ + h*HD_ + t];
    su2[t] = ws[WS_U2 + b*C_ + h*HD_ + t];
  }
  __syncthreads();
  if (t == 0) {
    float cs = 0.f;
    for (int j = 0; j < HD_; ++j) cs += (su1[j] + su2[j]) * bk[h*HD_ + j];
    ws[WS_CST + b*H_ + h] = cs;
  }
  for (int jj = 0; jj < 4; ++jj) {
    int c = t + 256 * jj;
    float a1 = 0.f, a2 = 0.f;
    #pragma unroll
    for (int j = 0; j < HD_; ++j) {
      float w = Wk[(size_t)(h*HD_ + j) * C_ + c];
      a1 += su1[j] * w;
      a2 += su2[j] * w;
    }
    ws[WS_A1 + (size_t)(b*H_ + h)*C_ + c] = a1;
    ws[WS_A2 + (size_t)(b*H_ + h)*C_ + c] = a2;
  }
}

// ---------------- flash: one pass over fvec_seq + dis_enc_seq ----------------
__global__ __launch_bounds__(512, 1) void flash(
    const float* __restrict__ fvec_seq, const float* __restrict__ dis_enc_seq,
    float* __restrict__ ws) {
  int b = blockIdx.x, s = blockIdx.y;
  int t = threadIdx.x;
  int wv_ = t >> 6, ln = t & 63;
  int h0 = 2 * wv_, h1 = 2 * wv_ + 1;

  __shared__ float bx[2][RPI_][C_];
  __shared__ float bd[2][RPI_][C_];

  // resident A-slices: lane owns columns c = 4*ln + 256*j + i  (j<4, i<4)
  float A10[16], A11[16], A20[16], A21[16];
  {
    const float* a10 = ws + WS_A1 + (size_t)(b*H_ + h0)*C_;
    const float* a11 = ws + WS_A1 + (size_t)(b*H_ + h1)*C_;
    const float* a20 = ws + WS_A2 + (size_t)(b*H_ + h0)*C_;
    const float* a21 = ws + WS_A2 + (size_t)(b*H_ + h1)*C_;
    #pragma unroll
    for (int j = 0; j < 4; ++j) {
      int c = 4*ln + 256*j;
      *(float4*)&A10[4*j] = *(const float4*)(a10 + c);
      *(float4*)&A11[4*j] = *(const float4*)(a11 + c);
      *(float4*)&A20[4*j] = *(const float4*)(a20 + c);
      *(float4*)&A21[4*j] = *(const float4*)(a21 + c);
    }
  }
  float c0 = ws[WS_CST + b*H_ + h0];
  float c1 = ws[WS_CST + b*H_ + h1];

  float S0[16], S1[16];
  #pragma unroll
  for (int i = 0; i < 16; ++i) { S0[i] = 0.f; S1[i] = 0.f; }
  float m0 = -1e30f, m1 = -1e30f, Z0 = 0.f, Z1 = 0.f;

  const int l0 = s * RPB_;
  const float* xbase = fvec_seq    + ((size_t)b * L_ + l0) * C_;
  const float* dbase = dis_enc_seq + ((size_t)b * L_ + l0) * C_;  // (1,B,L,C)

  // prologue: stage iter 0 into buffer 0
  #pragma unroll
  for (int k = 0; k < 4; ++k) {
    int idx = t + 512 * k;                 // [0,2048): x slots then d slots
    int which = idx >> 10;
    int r = (idx >> 8) & 3;
    int off = (idx & 255) * 4;
    float4 v = *(const float4*)((which ? dbase : xbase) + r * C_ + off);
    if (which) *(float4*)&bd[0][r][off] = v; else *(float4*)&bx[0][r][off] = v;
  }
  __syncthreads();

  for (int it = 0; it < ITERS_; ++it) {
    int cur = it & 1, nxt = cur ^ 1;
    float4 st[4];
    bool have = (it + 1 < ITERS_);
    if (have) {   // T14: issue next-iter global loads early
      const float* xb = xbase + (size_t)(it + 1) * RPI_ * C_;
      const float* db = dbase + (size_t)(it + 1) * RPI_ * C_;
      #pragma unroll
      for (int k = 0; k < 4; ++k) {
        int idx = t + 512 * k;
        int which = idx >> 10;
        int r = (idx >> 8) & 3;
        int off = (idx & 255) * 4;
        st[k] = *(const float4*)((which ? db : xb) + r * C_ + off);
      }
    }
    #pragma unroll
    for (int rr = 0; rr < RPI_; ++rr) {
      float4 xv[4], dv[4];
      #pragma unroll
      for (int j = 0; j < 4; ++j) {
        xv[j] = *(const float4*)&bx[cur][rr][4*ln + 256*j];
        dv[j] = *(const float4*)&bd[cur][rr][4*ln + 256*j];
      }
      float p0 = 0.f, p1 = 0.f;
      #pragma unroll
      for (int j = 0; j < 4; ++j) {
        const float* x4 = (const float*)&xv[j];
        const float* d4 = (const float*)&dv[j];
        #pragma unroll
        for (int i = 0; i < 4; ++i) {
          p0 += A10[4*j+i]*x4[i] + A20[4*j+i]*d4[i];
          p1 += A11[4*j+i]*x4[i] + A21[4*j+i]*d4[i];
        }
      }
      p0 = wave_sum_bcast(p0) + c0;
      p1 = wave_sum_bcast(p1) + c1;
      // online softmax update, head 0  (branches are wave-uniform)
      if (p0 > m0) {
        float fs = __expf(m0 - p0);
        Z0 *= fs;
        #pragma unroll
        for (int i = 0; i < 16; ++i) S0[i] *= fs;
        m0 = p0;
      }
      {
        float e = __expf(p0 - m0);
        Z0 += e;
        #pragma unroll
        for (int j = 0; j < 4; ++j) {
          const float* x4 = (const float*)&xv[j];
          #pragma unroll
          for (int i = 0; i < 4; ++i) S0[4*j+i] += e * x4[i];
        }
      }
      // head 1
      if (p1 > m1) {
        float fs = __expf(m1 - p1);
        Z1 *= fs;
        #pragma unroll
        for (int i = 0; i < 16; ++i) S1[i] *= fs;
        m1 = p1;
      }
      {
        float e = __expf(p1 - m1);
        Z1 += e;
        #pragma unroll
        for (int j = 0; j < 4; ++j) {
          const float* x4 = (const float*)&xv[j];
          #pragma unroll
          for (int i = 0; i < 4; ++i) S1[4*j+i] += e * x4[i];
        }
      }
    }
    if (have) {   // late LDS write into the other buffer
      #pragma unroll
      for (int k = 0; k < 4; ++k) {
        int idx = t + 512 * k;
        int which = idx >> 10;
        int r = (idx >> 8) & 3;
        int off = (idx & 255) * 4;
        if (which) *(float4*)&bd[nxt][r][off] = st[k]; else *(float4*)&bx[nxt][r][off] = st[k];
      }
    }
    __syncthreads();
  }

  // write per-split partials
  {
    float* sp0 = ws + WS_SP + ((size_t)(b*NS_ + s)*H_ + h0) * C_;
    float* sp1 = ws + WS_SP + ((size_t)(b*NS_ + s)*H_ + h1) * C_;
    #pragma unroll
    for (int j = 0; j < 4; ++j) {
      *(float4*)(sp0 + 4*ln + 256*j) = *(float4*)&S0[4*j];
      *(float4*)(sp1 + 4*ln + 256*j) = *(float4*)&S1[4*j];
    }
    if (ln == 0) {
      ws[WS_MP + (b*NS_ + s)*H_ + h0] = m0;
      ws[WS_MP + (b*NS_ + s)*H_ + h1] = m1;
      ws[WS_ZP + (b*NS_ + s)*H_ + h0] = Z0;
      ws[WS_ZP + (b*NS_ + s)*H_ + h1] = Z1;
    }
  }
}

// ---------------- combine splits -> sfin[b,h,c] = softmax-weighted sum of x rows ----------------
__global__ __launch_bounds__(256) void reduce_s(float* __restrict__ ws) {
  int b = blockIdx.x, h = blockIdx.y, t = threadIdx.x;
  float ms[NS_], wsc[NS_];
  float m = -1e30f;
  #pragma unroll
  for (int s = 0; s < NS_; ++s) {
    ms[s] = ws[WS_MP + (b*NS_ + s)*H_ + h];
    m = fmaxf(m, ms[s]);
  }
  float Z = 0.f;
  #pragma unroll
  for (int s = 0; s < NS_; ++s) {
    wsc[s] = __expf(ms[s] - m);
    Z += ws[WS_ZP + (b*NS_ + s)*H_ + h] * wsc[s];
  }
  float inv = 1.0f / Z;
  for (int jj = 0; jj < 4; ++jj) {
    int c = t + 256 * jj;
    float acc = 0.f;
    #pragma unroll
    for (int s = 0; s < NS_; ++s)
      acc += ws[WS_SP + ((size_t)(b*NS_ + s)*H_ + h)*C_ + c] * wsc[s];
    ws[WS_SFIN + (size_t)(b*H_ + h)*C_ + c] = acc * inv;
  }
}

// ---------------- v_o[b,i] = Wv[i,:]·sfin[b, i>>6, :] + bv[i] ----------------
__global__ __launch_bounds__(256) void vo_proj(
    const float* __restrict__ in_proj_w, const float* __restrict__ in_proj_b,
    float* __restrict__ ws) {
  int tid = blockIdx.x * 256 + threadIdx.x;
  int b = tid & (B_ - 1);
  int i = tid >> 5;
  const float* w = in_proj_w + (size_t)(2*C_ + i) * C_;
  const float* sf = ws + WS_SFIN + (size_t)(b*H_ + (i >> 6)) * C_;
  float acc = in_proj_b[2*C_ + i];
  for (int k = 0; k < C_; k += 4) {
    float4 a = *(const float4*)(w + k);
    float4 x = *(const float4*)(sf + k);
    acc += a.x*x.x + a.y*x.y + a.z*x.z + a.w*x.w;
  }
  ws[WS_VO + b*C_ + i] = acc;
}

// ---------------- o[b,j] = out_w[j,:]·vo[b,:] + out_b[j] ----------------
__global__ __launch_bounds__(256) void out_proj(
    const float* __restrict__ out_w, const float* __restrict__ out_b,
    float* __restrict__ ws) {
  int tid = blockIdx.x * 256 + threadIdx.x;
  int b = tid & (B_ - 1);
  int j = tid >> 5;
  const float* w = out_w + (size_t)j * C_;
  const float* x = ws + WS_VO + b*C_;
  float acc = out_b[j];
  for (int k = 0; k < C_; k += 4) {
    float4 a = *(const float4*)(w + k);
    float4 v = *(const float4*)(x + k);
    acc += a.x*v.x + a.y*v.y + a.z*v.z + a.w*v.w;
  }
  ws[WS_O + b*C_ + j] = acc;
}

// ---------------- LN1 -> w1 -> LN2 -> w2, one block per batch row ----------------
__global__ __launch_bounds__(256) void mlp_tail(
    const float* __restrict__ ln1_g, const float* __restrict__ ln1_b,
    const float* __restrict__ w1, const float* __restrict__ b1,
    const float* __restrict__ ln2_g, const float* __restrict__ ln2_b,
    const float* __restrict__ w2, const float* __restrict__ b2,
    const float* __restrict__ ws, float* __restrict__ out) {
  int b = blockIdx.x, t = threadIdx.x;
  __shared__ float xr[C_];
  __shared__ float xh[HID_];
  __shared__ float red[8];
  const float* o = ws + WS_O + b*C_;
  float v[4];
  float s = 0.f, sq = 0.f;
  #pragma unroll
  for (int j = 0; j < 4; ++j) {
    v[j] = o[t + 256*j];
    s += v[j];
    sq += v[j]*v[j];
  }
  s = wave_sum_bcast(s); sq = wave_sum_bcast(sq);
  int w = t >> 6;
  if ((t & 63) == 0) { red[w] = s; red[4+w] = sq; }
  __syncthreads();
  s  = red[0]+red[1]+red[2]+red[3];
  sq = red[4]+red[5]+red[6]+red[7];
  float mean = s * (1.f/1024.f);
  float var  = sq * (1.f/1024.f) - mean*mean;
  float rs = rsqrtf(var + 1e-5f);
  #pragma unroll
  for (int j = 0; j < 4; ++j) {
    int c = t + 256*j;
    xr[c] = (v[j] - mean) * rs * ln1_g[c] + ln1_b[c];
  }
  __syncthreads();
  // hidden = w1 @ xr + b1 (one output per thread)
  float acc = b1[t];
  const float* wr = w1 + (size_t)t * C_;
  for (int k = 0; k < C_; k += 4) {
    float4 a = *(const float4*)(wr + k);
    acc += a.x*xr[k] + a.y*xr[k+1] + a.z*xr[k+2] + a.w*xr[k+3];
  }
  float s2 = wave_sum_bcast(acc), sq2 = wave_sum_bcast(acc*acc);
  if ((t & 63) == 0) { red[w] = s2; red[4+w] = sq2; }
  __syncthreads();
  s2  = red[0]+red[1]+red[2]+red[3];
  sq2 = red[4]+red[5]+red[6]+red[7];
  float m2 = s2 * (1.f/256.f);
  float v2 = sq2 * (1.f/256.f) - m2*m2;
  float rs2 = rsqrtf(v2 + 1e-5f);
  xh[t] = (acc - m2) * rs2 * ln2_g[t] + ln2_b[t];
  __syncthreads();
  if (t < OUT_) {
    float a2 = b2[t];
    const float* wr2 = w2 + (size_t)t * HID_;
    for (int k = 0; k < HID_; k += 4) {
      float4 a = *(const float4*)(wr2 + k);
      a2 += a.x*xh[k] + a.y*xh[k+1] + a.z*xh[k+2] + a.w*xh[k+3];
    }
    out[b*OUT_ + t] = a2;
  }
}

extern "C" void kernel_launch(void* const* d_in, const int* in_sizes, int n_in,
                              void* d_out, int out_size, void* d_ws, size_t ws_size,
                              hipStream_t stream) {
  (void)in_sizes; (void)n_in; (void)out_size; (void)ws_size;
  const float* fvec_c      = (const float*)d_in[0];
  const float* fvec_seq    = (const float*)d_in[1];
  const float* dis_enc_c   = (const float*)d_in[2];
  const float* dis_enc_seq = (const float*)d_in[3];
  const float* in_proj_w   = (const float*)d_in[4];
  const float* in_proj_b   = (const float*)d_in[5];
  const float* out_w       = (const float*)d_in[6];
  const float* out_b       = (const float*)d_in[7];
  const float* ln1_g       = (const float*)d_in[8];
  const float* ln1_b       = (const float*)d_in[9];
  const float* w1          = (const float*)d_in[10];
  const float* b1          = (const float*)d_in[11];
  const float* ln2_g       = (const float*)d_in[12];
  const float* ln2_b       = (const float*)d_in[13];
  const float* w2          = (const float*)d_in[14];
  const float* b2          = (const float*)d_in[15];
  float* ws  = (float*)d_ws;
  float* out = (float*)d_out;

  prep_q  <<<dim3((B_*C_)/256), 256, 0, stream>>>(fvec_c, dis_enc_c, in_proj_w, in_proj_b, ws);
  prep_A  <<<dim3(B_, H_),      256, 0, stream>>>(in_proj_w + (size_t)C_*C_, in_proj_b + C_, ws);
  flash   <<<dim3(B_, NS_),     512, 0, stream>>>(fvec_seq, dis_enc_seq, ws);
  reduce_s<<<dim3(B_, H_),      256, 0, stream>>>(ws);
  vo_proj <<<dim3((B_*C_)/256), 256, 0, stream>>>(in_proj_w, in_proj_b, ws);
  out_proj<<<dim3((B_*C_)/256), 256, 0, stream>>>(out_w, out_b, ws);
  mlp_tail<<<dim3(B_),          256, 0, stream>>>(ln1_g, ln1_b, w1, b1, ln2_g, ln2_b, w2, b2, ws, out);
}

// Round 8
// 914.183 us; speedup vs baseline: 1.1400x; 1.1400x over previous
//
#include <hip/hip_runtime.h>
#include <hip/hip_bf16.h>
#include <cstdint>
#include <cstddef>

#define B_   32
#define L_   2048
#define C_   1024
#define H_   16
#define HD_  64
#define HID_ 256
#define OUT_ 128
#define NS_  16
#define RPB_ (L_/NS_)     // 128 rows per block

// ---------------- workspace layout (float offsets, all < 12M) ----------------
#define WS_U1   0
#define WS_U2   (WS_U1 + B_*C_)
#define WS_A1   (WS_U2 + B_*C_)
#define WS_A2   (WS_A1 + B_*H_*C_)
#define WS_CST  (WS_A2 + B_*H_*C_)
#define WS_G    (WS_CST + B_*H_)
#define WS_ZP   (WS_G + B_*L_*H_)
#define WS_SP   (WS_ZP + B_*NS_*H_)
#define WS_SFIN (WS_SP + B_*NS_*H_*C_)
#define WS_VO   (WS_SFIN + B_*H_*C_)
#define WS_O    (WS_VO + B_*C_)

// ---------------- DPP helpers ----------------
template <int CTRL>
__device__ __forceinline__ float dpp_add(float x) {
  int t = __builtin_amdgcn_update_dpp(0, __float_as_int(x), CTRL, 0xF, 0xF, true);
  return x + __int_as_float(t);
}
// full wave-64 sum, broadcast to all lanes
__device__ __forceinline__ float wave_sum_bcast(float x) {
  x = dpp_add<0x111>(x);  // row_shr:1
  x = dpp_add<0x112>(x);  // row_shr:2
  x = dpp_add<0x114>(x);  // row_shr:4
  x = dpp_add<0x118>(x);  // row_shr:8
  x = dpp_add<0x142>(x);  // row_bcast:15
  x = dpp_add<0x143>(x);  // row_bcast:31
  return __int_as_float(__builtin_amdgcn_readlane(__float_as_int(x), 63));
}
// sum over 8 contiguous lanes (sub = lane&7); result valid at sub==7
__device__ __forceinline__ float red8(float x) {
  x = dpp_add<0x114>(x);  // row_shr:4
  x = dpp_add<0x112>(x);  // row_shr:2
  x = dpp_add<0x111>(x);  // row_shr:1
  return x;
}

// ---------------- prep 1: u1 = q+q_r, u2 = q (wave per output) ----------------
__global__ __launch_bounds__(512) void prep_q(
    const float* __restrict__ fvec_c, const float* __restrict__ dis_enc_c,
    const float* __restrict__ in_proj_w, const float* __restrict__ in_proj_b,
    float* __restrict__ ws) {
  int t = threadIdx.x, wv = t >> 6, ln = t & 63;
  int task = blockIdx.x * 8 + wv;          // 32768 tasks
  int i = task >> 5, b = task & 31;
  const float4* wr = (const float4*)(in_proj_w + (size_t)i * C_) + ln * 4;
  const float4* xp = (const float4*)(fvec_c + b * C_) + ln * 4;
  const float4* dp = (const float4*)(dis_enc_c + b * C_) + ln * 4;
  float ax = 0.f, ad = 0.f;
  #pragma unroll
  for (int k = 0; k < 4; ++k) {
    float4 w = wr[k], x = xp[k], d = dp[k];
    ax += w.x*x.x + w.y*x.y + w.z*x.z + w.w*x.w;
    ad += w.x*d.x + w.y*d.y + w.z*d.z + w.w*d.w;
  }
  ax = wave_sum_bcast(ax); ad = wave_sum_bcast(ad);
  if (ln == 0) {
    float bq = in_proj_b[i];
    float q  = (ax + bq) * 0.125f;
    float qr = (ad + bq) * 0.125f;
    ws[WS_U1 + b*C_ + i] = q + qr;
    ws[WS_U2 + b*C_ + i] = q;
  }
}

// ---------------- prep 2: A1 = Wk_h^T u1_h ; A2 = Wk_h^T u2_h ; cst ----------------
__global__ __launch_bounds__(256) void prep_A(
    const float* __restrict__ Wk, const float* __restrict__ bk,
    float* __restrict__ ws) {
  int b = blockIdx.x, h = blockIdx.y, t = threadIdx.x;
  __shared__ float su1[HD_], su2[HD_];
  if (t < HD_) {
    su1[t] = ws[WS_U1 + b*C_ + h*HD_ + t];
    su2[t] = ws[WS_U2 + b*C_ + h*HD_ + t];
  }
  __syncthreads();
  if (t == 0) {
    float cs = 0.f;
    for (int j = 0; j < HD_; ++j) cs += (su1[j] + su2[j]) * bk[h*HD_ + j];
    ws[WS_CST + b*H_ + h] = cs;
  }
  for (int jj = 0; jj < 4; ++jj) {
    int c = t + 256 * jj;
    float a1 = 0.f, a2 = 0.f;
    #pragma unroll
    for (int j = 0; j < HD_; ++j) {
      float w = Wk[(size_t)(h*HD_ + j) * C_ + c];
      a1 += su1[j] * w;
      a2 += su2[j] * w;
    }
    ws[WS_A1 + (size_t)(b*H_ + h)*C_ + c] = a1;
    ws[WS_A2 + (size_t)(b*H_ + h)*C_ + c] = a2;
  }
}

// ---------------- pass D: g[b,l,h] = A2_h · d_l + cst ----------------
__global__ __launch_bounds__(1024, 4) void pass_d(
    const float* __restrict__ dis_enc_seq, float* __restrict__ ws) {
  int b = blockIdx.x, spl = blockIdx.y;
  int t = threadIdx.x, wv = t >> 6, ln = t & 63;
  int s = ln >> 3, sub = ln & 7;
  int h0 = 2*s, h1 = 2*s + 1;
  int cb = wv*64 + sub*8;

  __shared__ float bd[2][4][C_];      // 32 KB
  __shared__ float part[4][16][16];   // 4 KB

  float A2a[8], A2b[8];
  {
    const float* pa = ws + WS_A2 + (size_t)(b*H_ + h0)*C_ + cb;
    const float* pb = ws + WS_A2 + (size_t)(b*H_ + h1)*C_ + cb;
    *(float4*)&A2a[0] = *(const float4*)pa; *(float4*)&A2a[4] = *(const float4*)(pa+4);
    *(float4*)&A2b[0] = *(const float4*)pb; *(float4*)&A2b[4] = *(const float4*)(pb+4);
  }
  float csth = ws[WS_CST + b*H_ + (ln & 15)];
  const float* dbase = dis_enc_seq + ((size_t)b*L_ + spl*RPB_)*C_;   // (1,B,L,C)
  float* gdst = ws + WS_G + ((size_t)b*L_ + spl*RPB_)*H_;

  // stage group 0 -> buf 0 (4 rows x 1024 floats, 1 float4/thread, linear)
  {
    int r = wv >> 2, seg = wv & 3;
    float* dst = &bd[0][r][seg*256];
    const float* src = dbase + (size_t)r*C_ + seg*256 + ln*4;
    __builtin_amdgcn_global_load_lds(src, dst, 16, 0, 0);
  }
  __syncthreads();

  for (int g = 0; g < RPB_/4; ++g) {
    int cur = g & 1;
    if (g + 1 < RPB_/4) {     // prefetch next group into other buffer
      int r = wv >> 2, seg = wv & 3;
      float* dst = &bd[cur^1][r][seg*256];
      const float* src = dbase + (size_t)((g+1)*4 + r)*C_ + seg*256 + ln*4;
      __builtin_amdgcn_global_load_lds(src, dst, 16, 0, 0);
    }
    #pragma unroll
    for (int r = 0; r < 4; ++r) {
      float dv[8];
      *(float4*)&dv[0] = *(const float4*)&bd[cur][r][cb];
      *(float4*)&dv[4] = *(const float4*)&bd[cur][r][cb+4];
      float p0 = 0.f, p1 = 0.f;
      #pragma unroll
      for (int j = 0; j < 8; ++j) { p0 += A2a[j]*dv[j]; p1 += A2b[j]*dv[j]; }
      p0 = red8(p0); p1 = red8(p1);
      if (sub == 7) *(float2*)&part[r][wv][2*s] = make_float2(p0, p1);
    }
    __syncthreads();   // part ready (also drains prefetch)
    if (wv == 0) {
      int h = ln & 15, r = ln >> 4;
      float ps = 0.f;
      #pragma unroll
      for (int w2 = 0; w2 < 16; ++w2) ps += part[r][w2][h];
      gdst[(size_t)(g*4 + r)*H_ + h] = ps + csth;
    }
    __syncthreads();   // protect part from next group's writes
  }
}

// ---------------- flash X: p = A1·x + g ; e = exp(p) ; S += e·x ; Z += e ----------------
__global__ __launch_bounds__(1024, 4) void flash_x(
    const float* __restrict__ fvec_seq, float* __restrict__ ws) {
  int b = blockIdx.x, spl = blockIdx.y;
  int t = threadIdx.x, wv = t >> 6, ln = t & 63;
  int s = ln >> 3, sub = ln & 7;
  int h0 = 2*s, h1 = 2*s + 1;
  int cb = wv*64 + sub*8;

  __shared__ float bx[2][2][C_];      // 16 KB
  __shared__ float part[2][16][16];   // 2 KB
  __shared__ float ebuf[2][16];
  __shared__ float zred[2][16];

  float A1a[8], A1b[8];
  {
    const float* pa = ws + WS_A1 + (size_t)(b*H_ + h0)*C_ + cb;
    const float* pb = ws + WS_A1 + (size_t)(b*H_ + h1)*C_ + cb;
    *(float4*)&A1a[0] = *(const float4*)pa; *(float4*)&A1a[4] = *(const float4*)(pa+4);
    *(float4*)&A1b[0] = *(const float4*)pb; *(float4*)&A1b[4] = *(const float4*)(pb+4);
  }
  float S0[8], S1[8];
  #pragma unroll
  for (int j = 0; j < 8; ++j) { S0[j] = 0.f; S1[j] = 0.f; }
  float zacc = 0.f;

  const float* xbase = fvec_seq + ((size_t)b*L_ + spl*RPB_)*C_;
  const float* gsrc  = ws + WS_G + ((size_t)b*L_ + spl*RPB_)*H_;

  // stage group 0 (2 rows; waves 0..7 only)
  if (wv < 8) {
    int r = wv >> 2, seg = wv & 3;
    float* dst = &bx[0][r][seg*256];
    const float* src = xbase + (size_t)r*C_ + seg*256 + ln*4;
    __builtin_amdgcn_global_load_lds(src, dst, 16, 0, 0);
  }
  __syncthreads();

  for (int g = 0; g < RPB_/2; ++g) {
    int cur = g & 1;
    if (g + 1 < RPB_/2) {
      if (wv < 8) {
        int r = wv >> 2, seg = wv & 3;
        float* dst = &bx[cur^1][r][seg*256];
        const float* src = xbase + (size_t)((g+1)*2 + r)*C_ + seg*256 + ln*4;
        __builtin_amdgcn_global_load_lds(src, dst, 16, 0, 0);
      }
    }
    // dot phase: rows 0,1 of current buffer
    float x0[8], x1[8];
    *(float4*)&x0[0] = *(const float4*)&bx[cur][0][cb];
    *(float4*)&x0[4] = *(const float4*)&bx[cur][0][cb+4];
    *(float4*)&x1[0] = *(const float4*)&bx[cur][1][cb];
    *(float4*)&x1[4] = *(const float4*)&bx[cur][1][cb+4];
    float p00 = 0.f, p01 = 0.f, p10 = 0.f, p11 = 0.f;
    #pragma unroll
    for (int j = 0; j < 8; ++j) {
      p00 += A1a[j]*x0[j]; p01 += A1b[j]*x0[j];
      p10 += A1a[j]*x1[j]; p11 += A1b[j]*x1[j];
    }
    p00 = red8(p00); p01 = red8(p01); p10 = red8(p10); p11 = red8(p11);
    if (sub == 7) {
      *(float2*)&part[0][wv][2*s] = make_float2(p00, p01);
      *(float2*)&part[1][wv][2*s] = make_float2(p10, p11);
    }
    __syncthreads();   // part ready (also drains prefetch vmcnt)
    if (wv == 0 && ln < 32) {
      int h = ln & 15, r = ln >> 4;
      float ps = 0.f;
      #pragma unroll
      for (int w2 = 0; w2 < 16; ++w2) ps += part[r][w2][h];
      float e = __expf(ps + gsrc[(size_t)(g*2 + r)*H_ + h]);
      zacc += e;
      ebuf[r][h] = e;
    }
    __syncthreads();   // ebuf ready
    float2 e0 = *(const float2*)&ebuf[0][2*s];
    float2 e1 = *(const float2*)&ebuf[1][2*s];
    #pragma unroll
    for (int j = 0; j < 8; ++j) {
      S0[j] += e0.x*x0[j] + e1.x*x1[j];
      S1[j] += e0.y*x0[j] + e1.y*x1[j];
    }
  }
  // epilogue: S partials + Z
  {
    float* sp0 = ws + WS_SP + ((size_t)((b*NS_ + spl)*H_ + h0))*C_ + cb;
    float* sp1 = ws + WS_SP + ((size_t)((b*NS_ + spl)*H_ + h1))*C_ + cb;
    #pragma unroll
    for (int j = 0; j < 8; ++j) { sp0[j] = S0[j]; sp1[j] = S1[j]; }
  }
  __syncthreads();
  if (wv == 0 && ln < 32) zred[ln >> 4][ln & 15] = zacc;
  __syncthreads();
  if (t < 16) ws[WS_ZP + (b*NS_ + spl)*H_ + t] = zred[0][t] + zred[1][t];
}

// ---------------- combine splits: sfin = (sum SP) / (sum ZP) ----------------
__global__ __launch_bounds__(256) void reduce_s(float* __restrict__ ws) {
  int b = blockIdx.x, h = blockIdx.y, t = threadIdx.x;
  float Z = 0.f;
  #pragma unroll
  for (int sp = 0; sp < NS_; ++sp) Z += ws[WS_ZP + (b*NS_ + sp)*H_ + h];
  float inv = 1.0f / Z;
  #pragma unroll
  for (int jj = 0; jj < 4; ++jj) {
    int c = t + 256 * jj;
    float acc = 0.f;
    #pragma unroll
    for (int sp = 0; sp < NS_; ++sp)
      acc += ws[WS_SP + ((size_t)((b*NS_ + sp)*H_ + h))*C_ + c];
    ws[WS_SFIN + (size_t)(b*H_ + h)*C_ + c] = acc * inv;
  }
}

// ---------------- v_o (wave per output) ----------------
__global__ __launch_bounds__(512) void vo_proj(
    const float* __restrict__ in_proj_w, const float* __restrict__ in_proj_b,
    float* __restrict__ ws) {
  int t = threadIdx.x, wv = t >> 6, ln = t & 63;
  int task = blockIdx.x * 8 + wv;
  int i = task >> 5, b = task & 31;
  const float4* wr = (const float4*)(in_proj_w + (size_t)(2*C_ + i)*C_) + ln * 4;
  const float4* sf = (const float4*)(ws + WS_SFIN + (size_t)(b*H_ + (i >> 6))*C_) + ln * 4;
  float acc = 0.f;
  #pragma unroll
  for (int k = 0; k < 4; ++k) {
    float4 a = wr[k], x = sf[k];
    acc += a.x*x.x + a.y*x.y + a.z*x.z + a.w*x.w;
  }
  acc = wave_sum_bcast(acc);
  if (ln == 0) ws[WS_VO + b*C_ + i] = acc + in_proj_b[2*C_ + i];
}

// ---------------- out projection (wave per output) ----------------
__global__ __launch_bounds__(512) void out_proj(
    const float* __restrict__ out_w, const float* __restrict__ out_b,
    float* __restrict__ ws) {
  int t = threadIdx.x, wv = t >> 6, ln = t & 63;
  int task = blockIdx.x * 8 + wv;
  int j = task >> 5, b = task & 31;
  const float4* wr = (const float4*)(out_w + (size_t)j * C_) + ln * 4;
  const float4* xp = (const float4*)(ws + WS_VO + (size_t)b * C_) + ln * 4;
  float acc = 0.f;
  #pragma unroll
  for (int k = 0; k < 4; ++k) {
    float4 a = wr[k], x = xp[k];
    acc += a.x*x.x + a.y*x.y + a.z*x.z + a.w*x.w;
  }
  acc = wave_sum_bcast(acc);
  if (ln == 0) ws[WS_O + b*C_ + j] = acc + out_b[j];
}

// ---------------- LN1 -> w1 -> LN2 -> w2 (16 waves per batch row) ----------------
__global__ __launch_bounds__(1024) void mlp_tail(
    const float* __restrict__ ln1_g, const float* __restrict__ ln1_b,
    const float* __restrict__ w1, const float* __restrict__ b1,
    const float* __restrict__ ln2_g, const float* __restrict__ ln2_b,
    const float* __restrict__ w2, const float* __restrict__ b2,
    const float* __restrict__ ws, float* __restrict__ out) {
  int b = blockIdx.x, t = threadIdx.x, wv = t >> 6, ln = t & 63;
  __shared__ float xr[C_];
  __shared__ float xh[HID_];
  __shared__ float red[32];
  float v = ws[WS_O + b*C_ + t];
  float sv = wave_sum_bcast(v), sq = wave_sum_bcast(v*v);
  if (ln == 0) { red[wv] = sv; red[16+wv] = sq; }
  __syncthreads();
  float s = 0.f, q = 0.f;
  #pragma unroll
  for (int i = 0; i < 16; ++i) { s += red[i]; q += red[16+i]; }
  float mean = s * (1.f/1024.f);
  float var  = q * (1.f/1024.f) - mean*mean;
  float rs = rsqrtf(var + 1e-5f);
  xr[t] = (v - mean)*rs*ln1_g[t] + ln1_b[t];
  __syncthreads();
  // w1: wave wv computes rows wv*16 .. wv*16+15
  float hv[16];
  #pragma unroll
  for (int k = 0; k < 16; ++k) {
    int r = wv*16 + k;
    const float4* wr = (const float4*)(w1 + (size_t)r*C_) + ln*4;
    const float4* xp = (const float4*)xr + ln*4;
    float acc = 0.f;
    #pragma unroll
    for (int kk = 0; kk < 4; ++kk) {
      float4 a = wr[kk], x = xp[kk];
      acc += a.x*x.x + a.y*x.y + a.z*x.z + a.w*x.w;
    }
    acc = wave_sum_bcast(acc);
    hv[k] = acc + b1[r];
  }
  float s2 = 0.f, q2 = 0.f;
  #pragma unroll
  for (int k = 0; k < 16; ++k) { s2 += hv[k]; q2 += hv[k]*hv[k]; }
  if (ln == 0) { red[wv] = s2; red[16+wv] = q2; }
  __syncthreads();
  s2 = 0.f; q2 = 0.f;
  #pragma unroll
  for (int i = 0; i < 16; ++i) { s2 += red[i]; q2 += red[16+i]; }
  float m2 = s2*(1.f/256.f), v2 = q2*(1.f/256.f) - m2*m2;
  float rs2 = rsqrtf(v2 + 1e-5f);
  if (ln == 0) {
    #pragma unroll
    for (int k = 0; k < 16; ++k) {
      int r = wv*16 + k;
      xh[r] = (hv[k]-m2)*rs2*ln2_g[r] + ln2_b[r];
    }
  }
  __syncthreads();
  // w2: wave wv computes outputs wv*8 .. wv*8+7
  #pragma unroll
  for (int k = 0; k < 8; ++k) {
    int j = wv*8 + k;
    float4 a = *((const float4*)(w2 + (size_t)j*HID_) + ln);
    float4 x = *((const float4*)xh + ln);
    float acc = a.x*x.x + a.y*x.y + a.z*x.z + a.w*x.w;
    acc = wave_sum_bcast(acc);
    if (ln == 0) out[b*OUT_ + j] = acc + b2[j];
  }
}

extern "C" void kernel_launch(void* const* d_in, const int* in_sizes, int n_in,
                              void* d_out, int out_size, void* d_ws, size_t ws_size,
                              hipStream_t stream) {
  (void)in_sizes; (void)n_in; (void)out_size; (void)ws_size;
  const float* fvec_c      = (const float*)d_in[0];
  const float* fvec_seq    = (const float*)d_in[1];
  const float* dis_enc_c   = (const float*)d_in[2];
  const float* dis_enc_seq = (const float*)d_in[3];
  const float* in_proj_w   = (const float*)d_in[4];
  const float* in_proj_b   = (const float*)d_in[5];
  const float* out_w       = (const float*)d_in[6];
  const float* out_b       = (const float*)d_in[7];
  const float* ln1_g       = (const float*)d_in[8];
  const float* ln1_b       = (const float*)d_in[9];
  const float* w1          = (const float*)d_in[10];
  const float* b1          = (const float*)d_in[11];
  const float* ln2_g       = (const float*)d_in[12];
  const float* ln2_b       = (const float*)d_in[13];
  const float* w2          = (const float*)d_in[14];
  const float* b2          = (const float*)d_in[15];
  float* ws  = (float*)d_ws;
  float* out = (float*)d_out;

  prep_q  <<<dim3((B_*C_)/8), 512, 0, stream>>>(fvec_c, dis_enc_c, in_proj_w, in_proj_b, ws);
  prep_A  <<<dim3(B_, H_),    256, 0, stream>>>(in_proj_w + (size_t)C_*C_, in_proj_b + C_, ws);
  pass_d  <<<dim3(B_, NS_),  1024, 0, stream>>>(dis_enc_seq, ws);
  flash_x <<<dim3(B_, NS_),  1024, 0, stream>>>(fvec_seq, ws);
  reduce_s<<<dim3(B_, H_),    256, 0, stream>>>(ws);
  vo_proj <<<dim3((B_*C_)/8), 512, 0, stream>>>(in_proj_w, in_proj_b, ws);
  out_proj<<<dim3((B_*C_)/8), 512, 0, stream>>>(out_w, out_b, ws);
  mlp_tail<<<dim3(B_),       1024, 0, stream>>>(ln1_g, ln1_b, w1, b1, ln2_g, ln2_b, w2, b2, ws, out);
}